// Round 10
// baseline (138.527 us; speedup 1.0000x reference)
//
#include <hip/hip_runtime.h>
#include <hip/hip_bf16.h>

// ---------------------------------------------------------------------------
// EuclideanDeconf: out[b,c] = (2*dot(x[b],W[c]) - ||x[b]||^2 - ||W[c]||^2) / D
// R16: LDS-free gemm via fragment-major workspace layout. R8-R15 proved the
// LDS round-trip (DMA-write + ds_read + waits) is the invariant cost (MfmaUtil
// ~14% in both profiled variants). cvt now emits xb/wb in MFMA-fragment-major
// tiles: tile (mt=m>>5, kt=k>>6) is 2048B; element (m,k) at lane*32 + (k&31)
// where lane = (m&31)+32*((k>>5)&1) == exactly the 32x32x64 A/B fragment lane.
// gemm fragment loads = 2 coalesced global_load_dwordx4 per frag, straight to
// registers: NO LDS, no barriers, no ds_read, no bank conflicts. 3-deep reg
// ring (PD=3 tiles, ~800cy cover); WAITV(16) counted, drains only in 3 peeled
// tail iters. Grid (32,8) x-fastest => blocks sharing an A panel land on one
// XCD (id%8 = bx%8) => panel fetched once per XCD; 20 MB ws fits aggregate L2.
// KSPLIT=1 + fused epilogue kept from R14 (132.6us best).
// 128x128xBK64, 256 thr (4 waves 2x2, wave=64x64), grid (32,8)=256.
// ---------------------------------------------------------------------------

typedef float f32x4 __attribute__((ext_vector_type(4)));
typedef float f32x2 __attribute__((ext_vector_type(2)));
typedef float f32x16 __attribute__((ext_vector_type(16)));
typedef int i32x4 __attribute__((ext_vector_type(4)));
typedef int i32x8 __attribute__((ext_vector_type(8)));

#define BDIM 4096
#define DDIM 4096
#define CDIM 1024
#define TM 128
#define TN 128
#define BK 64
#define NIT (DDIM / BK)              // 64
#define SCALE 32.0f
#define INV_SS (1.0f/1024.0f)

#define WAITV(N) asm volatile("s_waitcnt vmcnt(" #N ")" ::: "memory")

// One WAVE per row: fp32 row -> fp8(e4m3, x SCALE) in FRAGMENT-MAJOR layout
// + fp32 sum-of-squares of the UNSCALED values.
// Lane l covers k-floats [l*64, l*64+64) = fp8 bytes [0,64) of k-tile kt=l.
// Dest: base + (row>>5)*131072 + l*2048 + (row&31)*32 + {0,16,1024,1040}.
__global__ __launch_bounds__(256) void cvt_rowsq(
    const float* __restrict__ x, const float* __restrict__ W,
    unsigned char* __restrict__ xb, unsigned char* __restrict__ wb,
    float* __restrict__ xsq, float* __restrict__ wsq)
{
    const int lane = threadIdx.x & 63;
    const int row = blockIdx.x * 4 + (threadIdx.x >> 6);

    const float* src;
    unsigned char* dstb;
    float* sq;
    int r;
    if (row < BDIM) {
        src = x + (size_t)row * DDIM;
        dstb = xb; r = row;
        sq = xsq + row;
    } else {
        r = row - BDIM;
        src = W + (size_t)r * DDIM;
        dstb = wb;
        sq = wsq + r;
    }

    const float4* s4 = (const float4*)src;
    float a = 0.f;
    unsigned int pk[16];
    #pragma unroll
    for (int u = 0; u < 16; ++u) {
        float4 f = s4[lane * 16 + u];
        a += f.x * f.x + f.y * f.y + f.z * f.z + f.w * f.w;
        unsigned int p = 0;
        p = __builtin_amdgcn_cvt_pk_fp8_f32(f.x * SCALE, f.y * SCALE, p, false);
        p = __builtin_amdgcn_cvt_pk_fp8_f32(f.z * SCALE, f.w * SCALE, p, true);
        pk[u] = p;
    }
    unsigned char* db = dstb + (size_t)(r >> 5) * 131072
                      + (size_t)lane * 2048 + (r & 31) * 32;
    i32x4 v0 = {(int)pk[0], (int)pk[1], (int)pk[2], (int)pk[3]};
    i32x4 v1 = {(int)pk[4], (int)pk[5], (int)pk[6], (int)pk[7]};
    i32x4 v2 = {(int)pk[8], (int)pk[9], (int)pk[10], (int)pk[11]};
    i32x4 v3 = {(int)pk[12], (int)pk[13], (int)pk[14], (int)pk[15]};
    *(i32x4*)(db)        = v0;
    *(i32x4*)(db + 16)   = v1;
    *(i32x4*)(db + 1024) = v2;
    *(i32x4*)(db + 1040) = v3;

    #pragma unroll
    for (int off = 32; off > 0; off >>= 1) a += __shfl_down(a, off);
    if (lane == 0) *sq = a;
}

// --- GEMM + fused epilogue, LDS-free ---
// Fragment tile (mt, kt): 2048B at (mt*64 + kt)*2048; lane l reads l*32+{0,16}.
// Wave (wr,wc) owns A frag-tiles mt0,mt0+1 and B frag-tiles nt0,nt0+1.
// Per k-tile: 8 coalesced global_load_dwordx4 -> 4 MXMFMA. PD=3 reg ring.

__device__ __forceinline__ i32x8 cat8(i32x4 lo, i32x4 hi) {
    return __builtin_shufflevector(lo, hi, 0, 1, 2, 3, 4, 5, 6, 7);
}

#define MXMFMA(A, Bv, C)                                                  \
    __builtin_amdgcn_mfma_scale_f32_32x32x64_f8f6f4(                      \
        (A), (Bv), (C), 0, 0, 0, 0x7F7F7F7F, 0, 0x7F7F7F7F)

struct FragS { i32x4 a0l, a0h, a1l, a1h, b0l, b0h, b1l, b1h; };

__global__ __launch_bounds__(256) void gemm_eucl(
    const unsigned char* __restrict__ xb,   // [B/32][64][64][32] fp8 frag-major
    const unsigned char* __restrict__ wb,   // [C/32][64][64][32] fp8 frag-major
    const float* __restrict__ xsq, const float* __restrict__ wsq,
    float* __restrict__ out)                // [B, C] fp32
{
    const int tid = threadIdx.x;
    const int lane = tid & 63;
    const int w = tid >> 6;                 // wave 0..3
    const int wr = w >> 1;                  // 0..1  (M half: 64 rows)
    const int wc = w & 1;                   // 0..1  (N half: 64 rows)
    const int bm = blockIdx.x * TM;
    const int bn = blockIdx.y * TN;

    // per-frag, per-lane base pointers (tile t at +t*2048)
    const int mt0 = (bm >> 5) + wr * 2;
    const int nt0 = (bn >> 5) + wc * 2;
    const unsigned char* pA0 = xb + (size_t)(mt0 + 0) * 131072 + (size_t)lane * 32;
    const unsigned char* pA1 = xb + (size_t)(mt0 + 1) * 131072 + (size_t)lane * 32;
    const unsigned char* pB0 = wb + (size_t)(nt0 + 0) * 131072 + (size_t)lane * 32;
    const unsigned char* pB1 = wb + (size_t)(nt0 + 1) * 131072 + (size_t)lane * 32;

#define LOADF(S, t)                                                       \
    do {                                                                  \
        (S).a0l = *(const i32x4*)(pA0 + (size_t)(t) * 2048);              \
        (S).a0h = *(const i32x4*)(pA0 + (size_t)(t) * 2048 + 16);         \
        (S).a1l = *(const i32x4*)(pA1 + (size_t)(t) * 2048);              \
        (S).a1h = *(const i32x4*)(pA1 + (size_t)(t) * 2048 + 16);         \
        (S).b0l = *(const i32x4*)(pB0 + (size_t)(t) * 2048);              \
        (S).b0h = *(const i32x4*)(pB0 + (size_t)(t) * 2048 + 16);         \
        (S).b1l = *(const i32x4*)(pB1 + (size_t)(t) * 2048);              \
        (S).b1h = *(const i32x4*)(pB1 + (size_t)(t) * 2048 + 16);         \
    } while (0)

    f32x16 acc[4] = {};   // [i 0..1][j 0..1] -> acc[i*2+j]

#define COMPUTE(S)                                                        \
    do {                                                                  \
        i32x8 fa0 = cat8((S).a0l, (S).a0h);                               \
        i32x8 fa1 = cat8((S).a1l, (S).a1h);                               \
        i32x8 fb0 = cat8((S).b0l, (S).b0h);                               \
        i32x8 fb1 = cat8((S).b1l, (S).b1h);                               \
        acc[0] = MXMFMA(fa0, fb0, acc[0]);                                \
        acc[1] = MXMFMA(fa0, fb1, acc[1]);                                \
        acc[2] = MXMFMA(fa1, fb0, acc[2]);                                \
        acc[3] = MXMFMA(fa1, fb1, acc[3]);                                \
    } while (0)

    FragS S[3];
    // prologue: tiles 0,1,2 in flight (24 loads)
    LOADF(S[0], 0);
    LOADF(S[1], 1);
    LOADF(S[2], 2);

    // main loop: WAITV(16) retires tile t's 8 loads (FIFO); t+1,t+2 flying;
    // then consume tile t and refill the slot with tile t+3.
    #pragma unroll
    for (int t = 0; t < NIT - 3; ++t) {
        WAITV(16);
        COMPUTE(S[t % 3]);
        LOADF(S[t % 3], t + 3);
    }
    WAITV(16); COMPUTE(S[1]);   // t=61
    WAITV(8);  COMPUTE(S[2]);   // t=62
    WAITV(0);  COMPUTE(S[0]);   // t=63

    // ---- fused epilogue ----
    // 32x32 C/D layout: col = lane&31, row = (reg&3)+8*(reg>>2)+4*(lane>>5).
    const float c1m = 2.0f * INV_SS / (float)DDIM;
    const float c2 = 1.0f / (float)DDIM;
    const int gn0 = bn + wc * 64 + (lane & 31);
    const int gm_b = bm + wr * 64 + (lane >> 5) * 4;
    const float wv0 = wsq[gn0];
    const float wv1 = wsq[gn0 + 32];
    #pragma unroll
    for (int i = 0; i < 2; ++i)
        #pragma unroll
        for (int g = 0; g < 4; ++g)
            #pragma unroll
            for (int rr = 0; rr < 4; ++rr) {
                const int gm = gm_b + i * 32 + g * 8 + rr;
                const float xs = xsq[gm];
                out[(size_t)gm * CDIM + gn0] =
                    acc[i * 2 + 0][g * 4 + rr] * c1m - (xs + wv0) * c2;
                out[(size_t)gm * CDIM + gn0 + 32] =
                    acc[i * 2 + 1][g * 4 + rr] * c1m - (xs + wv1) * c2;
            }
#undef LOADF
#undef COMPUTE
}

// --- Fallback: naive fp32 (any ws) ---
__global__ void fallback_kernel(const float* __restrict__ x, const float* __restrict__ W,
                                float* __restrict__ out)
{
    int c = blockIdx.x * blockDim.x + threadIdx.x;
    int b = blockIdx.y;
    if (c >= CDIM) return;
    const float* xr = x + (size_t)b * DDIM;
    const float* wr = W + (size_t)c * DDIM;
    float xs = 0.f, ws = 0.f, cr = 0.f;
    for (int d = 0; d < DDIM; ++d) {
        float xv = xr[d], wv = wr[d];
        xs += xv * xv; ws += wv * wv; cr += xv * wv;
    }
    out[(size_t)b * CDIM + c] = (2.0f * cr - xs - ws) / (float)DDIM;
}

extern "C" void kernel_launch(void* const* d_in, const int* in_sizes, int n_in,
                              void* d_out, int out_size, void* d_ws, size_t ws_size,
                              hipStream_t stream) {
    const float* x = (const float*)d_in[0];   // [B, D] fp32
    const float* W = (const float*)d_in[1];   // [C, D] fp32
    float* out = (float*)d_out;               // [B, C] fp32

    size_t need = (size_t)(BDIM + CDIM) * DDIM                 // fp8 inputs 20 MB
                + (size_t)(BDIM + CDIM) * sizeof(float);       // norms
    if (ws_size < need) {
        fallback_kernel<<<dim3(CDIM / 256, BDIM), 256, 0, stream>>>(x, W, out);
        return;
    }

    unsigned char* xb = (unsigned char*)d_ws;              // 16 MB (frag-major)
    unsigned char* wb = xb + (size_t)BDIM * DDIM;          // 4 MB (frag-major)
    float* xsq = (float*)(wb + (size_t)CDIM * DDIM);       // 16 KB
    float* wsq = xsq + BDIM;                               // 4 KB

    cvt_rowsq<<<(BDIM + CDIM) / 4, 256, 0, stream>>>(x, W, xb, wb, xsq, wsq);
    gemm_eucl<<<dim3(BDIM / TM, CDIM / TN), 256, 0, stream>>>(xb, wb, xsq, wsq, out);
}